// Round 1
// baseline (316.994 us; speedup 1.0000x reference)
//
#include <hip/hip_runtime.h>
#include <hip/hip_bf16.h>

// MultiHeadBatchedMixers: out[b,h,:,:] = sum_k w[b,h,k] * ( W2c_e @ ( GELU(W1c_e @ X @ W1t_e^T + B1_e) @ W2t_e^T ) + B2_e )
// e = expert_indices[b,h,k].  One block per (b,h,k), 4 waves, bf16 MFMA 16x16x32, f32 accum.

namespace {
constexpr int NHEAD = 12, NTOK = 256, HDIM = 64, HIDD = 512, NBATCH = 32, TOPK = 2;
// LDS layout (bytes). Pitches padded +16B so strided b128 reads are ~2-way (free) on 32 banks.
constexpr int SM_W1T = 0;      constexpr int P_W1T = NTOK * 2 + 16;  // 528; 32 rows (e) x 256 cols (n)
constexpr int SM_T1T = SM_W1T + 32 * P_W1T;                           // 16896
constexpr int P_T1T = HDIM * 2 + 16;                                  // 144; 32 rows (e) x 64 cols (d)
constexpr int SM_H = SM_T1T + 32 * P_T1T;                             // 21504
constexpr int P_H = 32 * 2 + 16;                                      // 80; 64 rows (c) x 32 cols (e)
constexpr int SM_T3T = SM_H + 64 * P_H;                               // 26624
constexpr int P_T3T = HDIM * 2 + 16;                                  // 144; per-wave: 64 rows (n) x 64 cols (c)
constexpr int SM_T3T_W = 64 * P_T3T;                                  // 9216
constexpr int SM_TOTAL = SM_T3T + 4 * SM_T3T_W;                       // 63488 < 64KB
}

typedef float f32x4 __attribute__((ext_vector_type(4)));
typedef short bf16x8 __attribute__((ext_vector_type(8)));
typedef short bf16x4 __attribute__((ext_vector_type(4)));

#define MFMA16(a, b, c) __builtin_amdgcn_mfma_f32_16x16x32_bf16((a), (b), (c), 0, 0, 0)

__device__ __forceinline__ short f2bf(float f) {
  // round-to-nearest-even bf16 (finite inputs only here)
  union { float f; unsigned u; } v; v.f = f;
  unsigned r = v.u + 0x7fffu + ((v.u >> 16) & 1u);
  return (short)(r >> 16);
}

__device__ __forceinline__ bf16x8 ld_gfrag(const float* p) {
  // 8 consecutive f32 (32B aligned) -> 8 bf16
  float4 a = *(const float4*)p;
  float4 b = *(const float4*)(p + 4);
  bf16x8 r;
  r[0] = f2bf(a.x); r[1] = f2bf(a.y); r[2] = f2bf(a.z); r[3] = f2bf(a.w);
  r[4] = f2bf(b.x); r[5] = f2bf(b.y); r[6] = f2bf(b.z); r[7] = f2bf(b.w);
  return r;
}

__device__ __forceinline__ float gelu_tanh(float x) {
  float x3 = x * x * x;
  return 0.5f * x * (1.0f + tanhf(0.7978845608028654f * (x + 0.044715f * x3)));
}

__global__ __launch_bounds__(256) void moe_mixer_kernel(
    const float* __restrict__ x, const int* __restrict__ eidx, const float* __restrict__ ewt,
    const float* __restrict__ w1t, const float* __restrict__ w1c, const float* __restrict__ b1,
    const float* __restrict__ w2t, const float* __restrict__ w2c, const float* __restrict__ b2,
    float* __restrict__ out) {
  __shared__ __align__(16) char smem[SM_TOTAL];

  const int bid = blockIdx.x;
  const int k = bid & 1;
  const int h = (bid >> 1) % NHEAD;
  const int b = bid / (TOPK * NHEAD);
  const int tid = threadIdx.x;
  const int w = tid >> 6;          // wave 0..3
  const int lane = tid & 63;
  const int lr = lane & 15;        // "row/col" lane index within 16
  const int lg = lane >> 4;        // k-group 0..3

  const int e = eidx[(b * NHEAD + h) * TOPK + k];
  const float wk = ewt[(b * NHEAD + h) * TOPK + k];

  const float* Xp  = x   + (size_t)(b * NHEAD + h) * HDIM * NTOK;
  const float* W1T = w1t + (size_t)(e * NHEAD + h) * HIDD * NTOK;
  const float* W1C = w1c + (size_t)(e * NHEAD + h) * HDIM * HDIM;
  const float* B1  = b1  + (size_t)(e * NHEAD + h) * HDIM * HIDD;
  const float* W2T = w2t + (size_t)(e * NHEAD + h) * NTOK * HIDD;
  const float* W2C = w2c + (size_t)(e * NHEAD + h) * HDIM * HDIM;
  const float* B2  = b2  + (size_t)(e * NHEAD + h) * HDIM * NTOK;
  float* OUT = out + (size_t)(b * NHEAD + h) * HDIM * NTOK;

  // ---- hoisted register fragments ----
  // X A-frags for this wave's d-tile (rows d = w*16+lr), k = token dim
  bf16x8 xf[8];
  {
    const float* xr = Xp + (w * 16 + lr) * NTOK;
    #pragma unroll
    for (int ks = 0; ks < 8; ++ks) xf[ks] = ld_gfrag(xr + ks * 32 + lg * 8);
  }
  // W1c B-frags: B[k=d][col=c], c = w*16+lr (this wave's c-tile), two 32-chunks of d
  bf16x8 w1cf[2];
  {
    const float* r = W1C + (w * 16 + lr) * HDIM + lg * 8;
    w1cf[0] = ld_gfrag(r);
    w1cf[1] = ld_gfrag(r + 32);
  }

  // T3 accumulators: this wave owns n in [w*64, w*64+64), all 64 c. [ct][nt]
  f32x4 acc3[4][4];
  #pragma unroll
  for (int ct = 0; ct < 4; ++ct)
    #pragma unroll
    for (int nt = 0; nt < 4; ++nt) acc3[ct][nt] = (f32x4){0.f, 0.f, 0.f, 0.f};

  // ---- HID tiles of 32 ----
  for (int t = 0; t < HIDD / 32; ++t) {
    const int hb = t * 32;

    // cooperative stage of W1t tile: rows e=hb..hb+31, all 256 n -> bf16 LDS
    {
      const int r = tid >> 3, cb = (tid & 7) * 32;
      const float* src = W1T + (size_t)(hb + r) * NTOK + cb;
      char* dst = smem + SM_W1T + r * P_W1T + cb * 2;
      #pragma unroll
      for (int m = 0; m < 4; ++m) *(bf16x8*)(dst + m * 16) = ld_gfrag(src + m * 8);
    }
    __syncthreads();

    // stage A: T1[d][e] = sum_n X[d,n]*W1t[e,n]; wave w does d-tile w, both e-tiles
    f32x4 a0 = {0.f, 0.f, 0.f, 0.f}, a1 = {0.f, 0.f, 0.f, 0.f};
    {
      const char* wrow0 = smem + SM_W1T + lr * P_W1T;
      const char* wrow1 = smem + SM_W1T + (16 + lr) * P_W1T;
      #pragma unroll
      for (int ks = 0; ks < 8; ++ks) {
        bf16x8 b0 = *(const bf16x8*)(wrow0 + ks * 64 + lg * 16);
        bf16x8 b1v = *(const bf16x8*)(wrow1 + ks * 64 + lg * 16);
        a0 = MFMA16(xf[ks], b0, a0);
        a1 = MFMA16(xf[ks], b1v, a1);
      }
    }
    // store T1^T[e][d]: D gives col=e=lr(+16et), row=d=w*16+lg*4+i (4 consecutive d -> 8B)
    {
      bf16x4 p0, p1;
      #pragma unroll
      for (int i = 0; i < 4; ++i) { p0[i] = f2bf(a0[i]); p1[i] = f2bf(a1[i]); }
      char* t1 = smem + SM_T1T + lr * P_T1T + (w * 16 + lg * 4) * 2;
      *(bf16x4*)t1 = p0;
      *(bf16x4*)(t1 + 16 * P_T1T) = p1;
    }
    __syncthreads();

    // stage B: T2^T[e][c] = sum_d T1^T[e][d]*W1c[c][d] + B1; wave w does c-tile w, both e-tiles
    {
      const float* b1p = B1 + (size_t)(w * 16 + lr) * HIDD + hb;
      f32x4 h0 = *(const f32x4*)(b1p + lg * 4);        // e = lg*4+i
      f32x4 h1 = *(const f32x4*)(b1p + 16 + lg * 4);   // e = 16+lg*4+i
      #pragma unroll
      for (int ks = 0; ks < 2; ++ks) {
        bf16x8 ae0 = *(const bf16x8*)(smem + SM_T1T + lr * P_T1T + ks * 64 + lg * 16);
        bf16x8 ae1 = *(const bf16x8*)(smem + SM_T1T + (16 + lr) * P_T1T + ks * 64 + lg * 16);
        h0 = MFMA16(ae0, w1cf[ks], h0);
        h1 = MFMA16(ae1, w1cf[ks], h1);
      }
      // gelu + store H[c][e] (row c = w*16+lr, 4 consecutive e -> 8B)
      bf16x4 g0, g1;
      #pragma unroll
      for (int i = 0; i < 4; ++i) { g0[i] = f2bf(gelu_tanh(h0[i])); g1[i] = f2bf(gelu_tanh(h1[i])); }
      char* hp = smem + SM_H + (w * 16 + lr) * P_H + lg * 8;
      *(bf16x4*)hp = g0;
      *(bf16x4*)(hp + 32) = g1;
    }
    __syncthreads();

    // stage C: T3[c][n] += sum_e H[c,e]*W2t[n,e]; wave w does n in [w*64, w*64+64)
    {
      bf16x8 af[4];
      #pragma unroll
      for (int ct = 0; ct < 4; ++ct)
        af[ct] = *(const bf16x8*)(smem + SM_H + (ct * 16 + lr) * P_H + lg * 16);
      #pragma unroll
      for (int nt = 0; nt < 4; ++nt) {
        const float* wr = W2T + (size_t)(w * 64 + nt * 16 + lr) * HIDD + hb + lg * 8;
        bf16x8 bfr = ld_gfrag(wr);
        #pragma unroll
        for (int ct = 0; ct < 4; ++ct) acc3[ct][nt] = MFMA16(af[ct], bfr, acc3[ct][nt]);
      }
    }
    // next iteration's W1t staging is fenced by the barrier after stage A stores
  }

  // ---- store T3^T per wave (no cross-wave sharing): rows n-local, cols c ----
  {
    char* t3 = smem + SM_T3T + w * SM_T3T_W;
    #pragma unroll
    for (int ct = 0; ct < 4; ++ct)
      #pragma unroll
      for (int nt = 0; nt < 4; ++nt) {
        bf16x4 p;
        #pragma unroll
        for (int i = 0; i < 4; ++i) p[i] = f2bf(acc3[ct][nt][i]);
        *(bf16x4*)(t3 + (nt * 16 + lr) * P_T3T + (ct * 16 + lg * 4) * 2) = p;
      }
  }
  __syncthreads();

  // ---- stage D: out^T[n][c_out] = sum_c T3^T[n][c]*W2c[c_out][c] ----
  bf16x8 w2cf[2][4];
  #pragma unroll
  for (int ks = 0; ks < 2; ++ks)
    #pragma unroll
    for (int cot = 0; cot < 4; ++cot)
      w2cf[ks][cot] = ld_gfrag(W2C + (size_t)(cot * 16 + lr) * HDIM + ks * 32 + lg * 8);

  f32x4 acc4[4][4];  // [nt][cot]
  #pragma unroll
  for (int nt = 0; nt < 4; ++nt)
    #pragma unroll
    for (int cot = 0; cot < 4; ++cot) acc4[nt][cot] = (f32x4){0.f, 0.f, 0.f, 0.f};

  {
    const char* t3 = smem + SM_T3T + w * SM_T3T_W;
    #pragma unroll
    for (int ks = 0; ks < 2; ++ks)
      #pragma unroll
      for (int nt = 0; nt < 4; ++nt) {
        bf16x8 a = *(const bf16x8*)(t3 + (nt * 16 + lr) * P_T3T + ks * 64 + lg * 16);
        #pragma unroll
        for (int cot = 0; cot < 4; ++cot) acc4[nt][cot] = MFMA16(a, w2cf[ks][cot], acc4[nt][cot]);
      }
  }

  // ---- epilogue: out[c_out][n] += wk*(acc4 + B2[c_out][n]) ----
  #pragma unroll
  for (int nt = 0; nt < 4; ++nt)
    #pragma unroll
    for (int cot = 0; cot < 4; ++cot) {
      const int n0 = w * 64 + nt * 16 + lg * 4;     // D row -> n
      const int co = cot * 16 + lr;                 // D col -> c_out
      const float4 bb = *(const float4*)(B2 + (size_t)co * NTOK + n0);
      float* op = OUT + (size_t)co * NTOK + n0;
      atomicAdd(op + 0, wk * (acc4[nt][cot][0] + bb.x));
      atomicAdd(op + 1, wk * (acc4[nt][cot][1] + bb.y));
      atomicAdd(op + 2, wk * (acc4[nt][cot][2] + bb.z));
      atomicAdd(op + 3, wk * (acc4[nt][cot][3] + bb.w));
    }
}

extern "C" void kernel_launch(void* const* d_in, const int* in_sizes, int n_in,
                              void* d_out, int out_size, void* d_ws, size_t ws_size,
                              hipStream_t stream) {
  const float* x   = (const float*)d_in[0];
  const int*   ei  = (const int*)d_in[1];
  const float* ew  = (const float*)d_in[2];
  const float* w1t = (const float*)d_in[3];
  const float* w1c = (const float*)d_in[4];
  const float* b1  = (const float*)d_in[5];
  const float* w2t = (const float*)d_in[6];
  const float* w2c = (const float*)d_in[7];
  const float* b2  = (const float*)d_in[8];
  float* out = (float*)d_out;

  // zero output (we combine top-k contributions with deterministic 2-way atomicAdd)
  hipMemsetAsync(out, 0, (size_t)out_size * sizeof(float), stream);

  dim3 grid(NBATCH * NHEAD * TOPK);
  moe_mixer_kernel<<<grid, dim3(256), 0, stream>>>(x, ei, ew, w1t, w1c, b1, w2t, w2c, b2, out);
}

// Round 3
// 226.400 us; speedup vs baseline: 1.4002x; 1.4002x over previous
//
#include <hip/hip_runtime.h>
#include <hip/hip_bf16.h>

// MultiHeadBatchedMixers, two-kernel structure:
//   Kernel A: H[bhk][c][e] = GELU(W1c @ X @ W1t^T + B1)   (bf16 workspace, 50.3 MB)
//   Kernel B: out[bh][co][n] = sum_k wk*(W2c @ (H_k @ W2t^T) + B2)
// bf16 MFMA 16x16x32, f32 accumulate. Barrier-light: A has 1 __syncthreads, B has 0.

namespace {
constexpr int NHEAD = 12, NTOK = 256, HDIM = 64, HIDD = 512, NBATCH = 32, TOPK = 2;
// Kernel A LDS: X tile [64 d][256 n] bf16 (pitch +16B) + per-wave T1^T [32 e][64 d]
constexpr int P_X  = NTOK * 2 + 16;   // 528
constexpr int SM_X = 0;
constexpr int SM_T1 = 64 * P_X;       // 33792
constexpr int P_T1 = HDIM * 2 + 16;   // 144
constexpr int T1_W = 32 * P_T1;       // 4608 per wave
constexpr int SMA_TOTAL = SM_T1 + 4 * T1_W;  // 52224
// Kernel B LDS: per-wave T3^T [32 n][64 c]
constexpr int P_T3 = HDIM * 2 + 16;   // 144
constexpr int T3_W = 32 * P_T3;       // 4608
constexpr int SMB_TOTAL = 4 * T3_W;   // 18432
}

typedef float f32x4 __attribute__((ext_vector_type(4)));
typedef short bf16x8 __attribute__((ext_vector_type(8)));
typedef short bf16x4 __attribute__((ext_vector_type(4)));

#define MFMA16(a, b, c) __builtin_amdgcn_mfma_f32_16x16x32_bf16((a), (b), (c), 0, 0, 0)

__device__ __forceinline__ short f2bf(float f) {
  union { float f; unsigned u; } v; v.f = f;
  unsigned r = v.u + 0x7fffu + ((v.u >> 16) & 1u);
  return (short)(r >> 16);
}

__device__ __forceinline__ bf16x8 ld_gfrag(const float* p) {
  float4 a = *(const float4*)p;
  float4 b = *(const float4*)(p + 4);
  bf16x8 r;
  r[0] = f2bf(a.x); r[1] = f2bf(a.y); r[2] = f2bf(a.z); r[3] = f2bf(a.w);
  r[4] = f2bf(b.x); r[5] = f2bf(b.y); r[6] = f2bf(b.z); r[7] = f2bf(b.w);
  return r;
}

__device__ __forceinline__ float gelu_tanh(float x) {
  // 0.5*x*(1+tanh(u)) = x*sigmoid(2u), u = 0.79788456*(x + 0.044715*x^3)
  float u = 0.7978845608028654f * x * (1.0f + 0.044715f * x * x);
  return x / (1.0f + __expf(-2.0f * u));
}

// ---------------- Kernel A ----------------
// grid = 768 * 4; block bx: bhk = bx>>2, e-block = (bx&3)*128. 4 waves; wave w owns
// e-local rows [w*32, w*32+32). Computes H[c][e] for its 128-e slab.
__global__ __launch_bounds__(256) void mixer_h_kernel(
    const float* __restrict__ x, const int* __restrict__ eidx,
    const float* __restrict__ w1t, const float* __restrict__ w1c, const float* __restrict__ b1,
    short* __restrict__ hws) {
  __shared__ __align__(16) char smem[SMA_TOTAL];
  const int bx = blockIdx.x;
  const int bhk = bx >> 2, eblk = bx & 3;
  const int h = (bhk >> 1) % NHEAD;
  const int tid = threadIdx.x, w = tid >> 6, lane = tid & 63, lr = lane & 15, lg = lane >> 4;

  const int e = eidx[bhk];
  const float* Xp = x + (size_t)(bhk >> 1) * HDIM * NTOK;
  const size_t eh = (size_t)e * NHEAD + h;
  const float* W1T = w1t + eh * HIDD * NTOK;
  const float* W1C = w1c + eh * HDIM * HDIM;
  const float* B1  = b1  + eh * HDIM * HIDD;
  short* H = hws + (size_t)bhk * HDIM * HIDD;

  // stage X (64x256 f32 -> bf16 LDS), one barrier
  {
    const int r = tid >> 2, seg = (tid & 3) * 64;
    const float* src = Xp + r * NTOK + seg;
    char* dst = smem + SM_X + r * P_X + seg * 2;
    #pragma unroll
    for (int m = 0; m < 8; ++m) *(bf16x8*)(dst + m * 16) = ld_gfrag(src + m * 8);
  }
  __syncthreads();

  const int e0 = eblk * 128 + w * 32;  // global e base for this wave

  // MFMA1: T1[d][e] = sum_n X[d,n]*W1t[e,n];  A=X (LDS, m=d), B=W1t (global, n=e), k=n
  // D layout: col=e=lane&15, row=d=(lane>>4)*4+reg  (round-1-verified orientation)
  f32x4 acc1[2][4];
  #pragma unroll
  for (int et = 0; et < 2; ++et)
    #pragma unroll
    for (int dt = 0; dt < 4; ++dt) acc1[et][dt] = (f32x4){0.f, 0.f, 0.f, 0.f};
  #pragma unroll
  for (int ks = 0; ks < 8; ++ks) {
    bf16x8 w0 = ld_gfrag(W1T + (size_t)(e0 + lr) * NTOK + ks * 32 + lg * 8);
    bf16x8 w1v = ld_gfrag(W1T + (size_t)(e0 + 16 + lr) * NTOK + ks * 32 + lg * 8);
    #pragma unroll
    for (int dt = 0; dt < 4; ++dt) {
      bf16x8 xf = *(const bf16x8*)(smem + SM_X + (dt * 16 + lr) * P_X + (ks * 32 + lg * 8) * 2);
      acc1[0][dt] = MFMA16(xf, w0, acc1[0][dt]);
      acc1[1][dt] = MFMA16(xf, w1v, acc1[1][dt]);
    }
  }

  // relayout T1^T via wave-private LDS (col=e=lr, row=d=dt*16+lg*4+i) -> [e][d] rows
  char* t1 = smem + SM_T1 + w * T1_W;
  #pragma unroll
  for (int et = 0; et < 2; ++et)
    #pragma unroll
    for (int dt = 0; dt < 4; ++dt) {
      bf16x4 p;
      #pragma unroll
      for (int i = 0; i < 4; ++i) p[i] = f2bf(acc1[et][dt][i]);
      *(bf16x4*)(t1 + (et * 16 + lr) * P_T1 + (dt * 16 + lg * 4) * 2) = p;
    }

  // MFMA2: T2^T[e][c] = sum_d T1^T[e,d] * W1c[c,d] + B1;  A=T1^T (LDS), B=W1c (global)
  f32x4 acc2[2][4];
  #pragma unroll
  for (int et = 0; et < 2; ++et)
    #pragma unroll
    for (int ct = 0; ct < 4; ++ct)
      acc2[et][ct] = *(const f32x4*)(B1 + (size_t)(ct * 16 + lr) * HIDD + e0 + et * 16 + lg * 4);
  #pragma unroll
  for (int ks = 0; ks < 2; ++ks) {
    bf16x8 a[2];
    #pragma unroll
    for (int et = 0; et < 2; ++et)
      a[et] = *(const bf16x8*)(t1 + (et * 16 + lr) * P_T1 + (ks * 32 + lg * 8) * 2);
    #pragma unroll
    for (int ct = 0; ct < 4; ++ct) {
      bf16x8 bfr = ld_gfrag(W1C + (size_t)(ct * 16 + lr) * HDIM + ks * 32 + lg * 8);
      #pragma unroll
      for (int et = 0; et < 2; ++et) acc2[et][ct] = MFMA16(a[et], bfr, acc2[et][ct]);
    }
  }

  // GELU + store H[c][e] (D2: col=c=lr, row=e=lg*4+i) -> 8B stores, e contiguous
  #pragma unroll
  for (int et = 0; et < 2; ++et)
    #pragma unroll
    for (int ct = 0; ct < 4; ++ct) {
      bf16x4 g;
      #pragma unroll
      for (int i = 0; i < 4; ++i) g[i] = f2bf(gelu_tanh(acc2[et][ct][i]));
      *(bf16x4*)(H + (size_t)(ct * 16 + lr) * HIDD + e0 + et * 16 + lg * 4) = g;
    }
}

// ---------------- Kernel B ----------------
// grid = 384 * 2; block bx: bh = bx>>1, n-tile base = (bx&1)*128. 4 waves; wave w owns
// n-local [w*32, w*32+32), all 64 co. k-loop inside, weighted combine in registers.
__global__ __launch_bounds__(256) void mixer_out_kernel(
    const int* __restrict__ eidx, const float* __restrict__ ewt,
    const float* __restrict__ w2t, const float* __restrict__ w2c, const float* __restrict__ b2,
    const short* __restrict__ hws, float* __restrict__ out) {
  __shared__ __align__(16) char smem[SMB_TOTAL];
  const int bx = blockIdx.x;
  const int bh = bx >> 1, h = bh % NHEAD;
  const int tid = threadIdx.x, w = tid >> 6, lane = tid & 63, lr = lane & 15, lg = lane >> 4;
  const int nb = (bx & 1) * 128 + w * 32;  // global n base for this wave
  char* t3 = smem + w * T3_W;
  float* OUT = out + (size_t)bh * HDIM * NTOK;

  f32x4 accO[2][4];
  #pragma unroll
  for (int nt = 0; nt < 2; ++nt)
    #pragma unroll
    for (int ct = 0; ct < 4; ++ct) accO[nt][ct] = (f32x4){0.f, 0.f, 0.f, 0.f};

  for (int k = 0; k < TOPK; ++k) {
    const int e = eidx[bh * TOPK + k];
    const float wk = ewt[bh * TOPK + k];
    const size_t eh = (size_t)e * NHEAD + h;
    const float* W2T = w2t + eh * NTOK * HIDD;
    const float* W2C = w2c + eh * HDIM * HDIM;
    const float* B2  = b2  + eh * HDIM * NTOK;
    const short* Hk = hws + (size_t)(bh * TOPK + k) * HDIM * HIDD;

    // MFMA3: T3[c][n] = sum_e H[c,e] * W2t[n,e];  A=H (global bf16, m=c), B=W2t (global, n=n)
    f32x4 acc3[4][2];
    #pragma unroll
    for (int ct = 0; ct < 4; ++ct)
      #pragma unroll
      for (int nt = 0; nt < 2; ++nt) acc3[ct][nt] = (f32x4){0.f, 0.f, 0.f, 0.f};
    #pragma unroll 4
    for (int ks = 0; ks < 16; ++ks) {
      bf16x8 a[4];
      #pragma unroll
      for (int ct = 0; ct < 4; ++ct)
        a[ct] = *(const bf16x8*)(Hk + (size_t)(ct * 16 + lr) * HIDD + ks * 32 + lg * 8);
      #pragma unroll
      for (int nt = 0; nt < 2; ++nt) {
        bf16x8 bfr = ld_gfrag(W2T + (size_t)(nb + nt * 16 + lr) * HIDD + ks * 32 + lg * 8);
        #pragma unroll
        for (int ct = 0; ct < 4; ++ct) acc3[ct][nt] = MFMA16(a[ct], bfr, acc3[ct][nt]);
      }
    }

    // relayout T3^T via wave-private LDS (D3: col=n=lr, row=c=lg*4+i) -> [n][c] rows
    #pragma unroll
    for (int ct = 0; ct < 4; ++ct)
      #pragma unroll
      for (int nt = 0; nt < 2; ++nt) {
        bf16x4 p;
        #pragma unroll
        for (int i = 0; i < 4; ++i) p[i] = f2bf(acc3[ct][nt][i]);
        *(bf16x4*)(t3 + (nt * 16 + lr) * P_T3 + (ct * 16 + lg * 4) * 2) = p;
      }

    // MFMA4: OUT^T[n][co] = sum_c T3^T[n,c] * W2c[co,c];  A=T3^T (LDS, m=n), B=W2c (global, n=co)
    f32x4 acc4[2][4];
    #pragma unroll
    for (int nt = 0; nt < 2; ++nt)
      #pragma unroll
      for (int ct = 0; ct < 4; ++ct) acc4[nt][ct] = (f32x4){0.f, 0.f, 0.f, 0.f};
    #pragma unroll
    for (int ks = 0; ks < 2; ++ks) {
      bf16x8 a[2];
      #pragma unroll
      for (int nt = 0; nt < 2; ++nt)
        a[nt] = *(const bf16x8*)(t3 + (nt * 16 + lr) * P_T3 + (ks * 32 + lg * 8) * 2);
      #pragma unroll
      for (int ct = 0; ct < 4; ++ct) {
        bf16x8 bfr = ld_gfrag(W2C + (size_t)(ct * 16 + lr) * HDIM + ks * 32 + lg * 8);
        #pragma unroll
        for (int nt = 0; nt < 2; ++nt) acc4[nt][ct] = MFMA16(a[nt], bfr, acc4[nt][ct]);
      }
    }

    // weighted accumulate: accO += wk * (acc4 + B2)   (D4: col=co=lr, row=n=lg*4+i)
    #pragma unroll
    for (int nt = 0; nt < 2; ++nt)
      #pragma unroll
      for (int ct = 0; ct < 4; ++ct) {
        f32x4 bb = *(const f32x4*)(B2 + (size_t)(ct * 16 + lr) * NTOK + nb + nt * 16 + lg * 4);
        #pragma unroll
        for (int i = 0; i < 4; ++i) accO[nt][ct][i] += wk * (acc4[nt][ct][i] + bb[i]);
      }
  }

  // store (each (co,n) written exactly once across the grid)
  #pragma unroll
  for (int nt = 0; nt < 2; ++nt)
    #pragma unroll
    for (int ct = 0; ct < 4; ++ct)
      *(f32x4*)(OUT + (size_t)(ct * 16 + lr) * NTOK + nb + nt * 16 + lg * 4) = accO[nt][ct];
}

extern "C" void kernel_launch(void* const* d_in, const int* in_sizes, int n_in,
                              void* d_out, int out_size, void* d_ws, size_t ws_size,
                              hipStream_t stream) {
  const float* x   = (const float*)d_in[0];
  const int*   ei  = (const int*)d_in[1];
  const float* ew  = (const float*)d_in[2];
  const float* w1t = (const float*)d_in[3];
  const float* w1c = (const float*)d_in[4];
  const float* b1  = (const float*)d_in[5];
  const float* w2t = (const float*)d_in[6];
  const float* w2c = (const float*)d_in[7];
  const float* b2  = (const float*)d_in[8];
  float* out = (float*)d_out;
  short* hws = (short*)d_ws;  // 768 * 64 * 512 bf16 = 50.3 MB

  mixer_h_kernel<<<dim3(NBATCH * NHEAD * TOPK * 4), dim3(256), 0, stream>>>(
      x, ei, w1t, w1c, b1, hws);
  mixer_out_kernel<<<dim3(NBATCH * NHEAD * 2), dim3(256), 0, stream>>>(
      ei, ew, w2t, w2c, b2, hws, out);
}